// Round 1
// baseline (182.099 us; speedup 1.0000x reference)
//
#include <hip/hip_runtime.h>
#include <hip/hip_bf16.h>
#include <cstdint>
#include <cstddef>

// ---------------------------------------------------------------------------
// KQV2DPixel: fused 1x1-conv projections + flash attention over N=4096 pixels
// B=8, C_IN=64, C_MID=32, N=64*64=4096. fp32 in/out.
// Split-bf16 (hi+lo) QK^T via mfma_f32_32x32x16_bf16, online softmax, PV in
// bf16, O accumulated transposed so rescale + output write are lane-local.
// ---------------------------------------------------------------------------

typedef __bf16 bf16x8 __attribute__((ext_vector_type(8)));
typedef float  f32x16 __attribute__((ext_vector_type(16)));

struct alignas(16) U4 { uint32_t w[4]; };

#define MFMA32(A, B, C) __builtin_amdgcn_mfma_f32_32x32x16_bf16((A), (B), (C), 0, 0, 0)

__device__ __forceinline__ uint16_t f2bf(float f) {
    uint32_t u = __builtin_bit_cast(uint32_t, f);
    u += 0x7fffu + ((u >> 16) & 1u);       // RNE
    return (uint16_t)(u >> 16);
}
__device__ __forceinline__ float bf2f(uint16_t h) {
    uint32_t u = ((uint32_t)h) << 16;
    return __builtin_bit_cast(float, u);
}
__device__ __forceinline__ uint32_t pk2(float lo, float hi) {
    return (uint32_t)f2bf(lo) | ((uint32_t)f2bf(hi) << 16);
}

// ---------------------------------------------------------------------------
// Kernel 1: projections. grid 128 x 256 threads; thread = one pixel n.
//   k,q: hi+lo bf16, layout [B][N][32] (pixel-major rows for MFMA frags)
//   v:   bf16, layout [B][32][N] (natural; serves as V^T)
// ---------------------------------------------------------------------------
__global__ __launch_bounds__(256) void proj_kernel(
    const float* __restrict__ x,
    const float* __restrict__ Wk, const float* __restrict__ bk,
    const float* __restrict__ Wq, const float* __restrict__ bq,
    const float* __restrict__ Wv, const float* __restrict__ bv,
    uint16_t* __restrict__ qhi, uint16_t* __restrict__ qlo,
    uint16_t* __restrict__ khi, uint16_t* __restrict__ klo,
    uint16_t* __restrict__ vt)
{
    __shared__ float Wl[32 * 64];
    __shared__ float bl[32];
    __shared__ __align__(16) uint16_t stg[256 * 32];   // 16 KB transpose stage

    const int tid   = threadIdx.x;
    const int b     = blockIdx.x >> 4;          // 16 blocks per batch
    const int nbase = (blockIdx.x & 15) << 8;   // 256 pixels per block
    const int n     = nbase + tid;
    const float* xb = x + (size_t)b * 64 * 4096 + n;

    for (int pass = 0; pass < 3; ++pass) {
        const float* W    = pass == 0 ? Wk : (pass == 1 ? Wq : Wv);
        const float* bias = pass == 0 ? bk : (pass == 1 ? bq : bv);
        __syncthreads();   // previous pass done with Wl/stg
        for (int i = tid; i < 2048; i += 256) Wl[i] = W[i];
        if (tid < 32) bl[tid] = bias[tid];
        __syncthreads();

        float acc[32];
        #pragma unroll
        for (int o = 0; o < 32; ++o) acc[o] = bl[o];
        for (int ci = 0; ci < 64; ++ci) {
            float xv = xb[(size_t)ci * 4096];
            #pragma unroll
            for (int o = 0; o < 32; ++o) acc[o] = fmaf(Wl[o * 64 + ci], xv, acc[o]);
        }

        if (pass == 2) {
            #pragma unroll
            for (int o = 0; o < 32; ++o)
                vt[((size_t)(b * 32 + o)) * 4096 + n] = f2bf(acc[o]);
        } else {
            uint16_t* hid = pass ? qhi : khi;
            uint16_t* lod = pass ? qlo : klo;
            U4* dsth = (U4*)(hid + ((size_t)(b * 4096 + nbase)) * 32);
            U4* dstl = (U4*)(lod + ((size_t)(b * 4096 + nbase)) * 32);
            #pragma unroll
            for (int o = 0; o < 32; ++o) stg[tid * 32 + o] = f2bf(acc[o]);
            __syncthreads();
            for (int i = tid; i < 1024; i += 256) dsth[i] = ((const U4*)stg)[i];
            __syncthreads();
            #pragma unroll
            for (int o = 0; o < 32; ++o) {
                uint16_t h = f2bf(acc[o]);
                stg[tid * 32 + o] = f2bf(acc[o] - bf2f(h));
            }
            __syncthreads();
            for (int i = tid; i < 1024; i += 256) dstl[i] = ((const U4*)stg)[i];
        }
    }
}

// ---------------------------------------------------------------------------
// Kernel 2: flash attention. grid 256 (XCD-swizzled: XCD x owns batch x),
// 256 threads = 4 waves, each wave owns 32 q rows (Q tile 128).
// K loop: 64-key tiles in LDS (K hi/lo rows padded to 80B, V^T rows to 144B).
// S^T = mfma(K, Q)  -> q-row lane-local softmax state.
// O^T accumulated via mfma(V^T, P^T) -> lane-local rescale + direct [C][N] out.
// ---------------------------------------------------------------------------
__global__ __launch_bounds__(256) void attn_kernel(
    const uint16_t* __restrict__ qhi, const uint16_t* __restrict__ qlo,
    const uint16_t* __restrict__ khi, const uint16_t* __restrict__ klo,
    const uint16_t* __restrict__ vt, float* __restrict__ out)
{
    __shared__ __align__(16) uint16_t lkh[64 * 40];   // K hi tile, 80B rows
    __shared__ __align__(16) uint16_t lkl[64 * 40];   // K lo tile
    __shared__ __align__(16) uint16_t lvt[32 * 72];   // V^T tile, 144B rows

    const int blk  = blockIdx.x;
    const int g    = (blk & 7) * 32 + (blk >> 3);  // XCD swizzle (256 % 8 == 0)
    const int b    = g >> 5;                       // 32 blocks per batch
    const int qblk = g & 31;
    const int tid  = threadIdx.x;
    const int wv   = tid >> 6;
    const int lane = tid & 63;
    const int l31  = lane & 31;
    const int h32  = lane >> 5;
    const int qrow = qblk * 128 + wv * 32 + l31;   // this lane's q row

    // Q fragments: B-operand layout = col(lane&31)=q, c = 8*(lane>>5)+j
    bf16x8 qh[2], ql[2];
    {
        const uint16_t* r = qhi + ((size_t)(b * 4096 + qrow)) * 32;
        qh[0] = __builtin_bit_cast(bf16x8, *(const U4*)(r + h32 * 8));
        qh[1] = __builtin_bit_cast(bf16x8, *(const U4*)(r + 16 + h32 * 8));
        const uint16_t* r2 = qlo + ((size_t)(b * 4096 + qrow)) * 32;
        ql[0] = __builtin_bit_cast(bf16x8, *(const U4*)(r2 + h32 * 8));
        ql[1] = __builtin_bit_cast(bf16x8, *(const U4*)(r2 + 16 + h32 * 8));
    }

    f32x16 oacc;
    #pragma unroll
    for (int i = 0; i < 16; ++i) oacc[i] = 0.f;
    float m_run = -3.0e38f, l_run = 0.f;

    const U4* gkh = (const U4*)(khi + ((size_t)b * 4096) * 32);
    const U4* gkl = (const U4*)(klo + ((size_t)b * 4096) * 32);
    const uint16_t* gv = vt + ((size_t)b * 32) * 4096;

    for (int kb = 0; kb < 64; ++kb) {
        // ---- stage K hi/lo (64x32 bf16 each) and V^T (32x64 bf16) ----
        {
            U4 a = gkh[kb * 256 + tid];
            U4 c = gkl[kb * 256 + tid];
            U4 v = *(const U4*)(gv + ((size_t)(tid >> 3)) * 4096 + kb * 64 + (tid & 7) * 8);
            *(U4*)((char*)lkh + (tid >> 2) * 80 + (tid & 3) * 16) = a;
            *(U4*)((char*)lkl + (tid >> 2) * 80 + (tid & 3) * 16) = c;
            *(U4*)((char*)lvt + (tid >> 3) * 144 + (tid & 7) * 16) = v;
        }
        __syncthreads();

        #pragma unroll
        for (int ks = 0; ks < 2; ++ks) {
            // K fragments: A row(lane&31)=k, c = 8*(lane>>5)+j
            const char* kr = (const char*)lkh + (ks * 32 + l31) * 80 + h32 * 16;
            const char* lr = (const char*)lkl + (ks * 32 + l31) * 80 + h32 * 16;
            bf16x8 kh0 = __builtin_bit_cast(bf16x8, *(const U4*)kr);
            bf16x8 kh1 = __builtin_bit_cast(bf16x8, *(const U4*)(kr + 32));
            bf16x8 kl0 = __builtin_bit_cast(bf16x8, *(const U4*)lr);
            bf16x8 kl1 = __builtin_bit_cast(bf16x8, *(const U4*)(lr + 32));

            f32x16 s;
            #pragma unroll
            for (int i = 0; i < 16; ++i) s[i] = 0.f;
            // S^T[k][q] = sum_c K[k][c] Q[q][c]; split: qh*kh + qh*kl + ql*kh
            s = MFMA32(kh0, qh[0], s);
            s = MFMA32(kh1, qh[1], s);
            s = MFMA32(kl0, qh[0], s);
            s = MFMA32(kl1, qh[1], s);
            s = MFMA32(kh0, ql[0], s);
            s = MFMA32(kh1, ql[1], s);

            // ---- online softmax: lane holds 16 of 32 keys for q=l31 ----
            float pm = s[0];
            #pragma unroll
            for (int i = 1; i < 16; ++i) pm = fmaxf(pm, s[i]);
            pm = fmaxf(pm, __shfl_xor(pm, 32));
            float mn = fmaxf(m_run, pm);
            float sc = __expf(m_run - mn);
            float p[16];
            float rs = 0.f;
            #pragma unroll
            for (int i = 0; i < 16; ++i) { p[i] = __expf(s[i] - mn); rs += p[i]; }
            rs += __shfl_xor(rs, 32);
            l_run = l_run * sc + rs;
            m_run = mn;
            #pragma unroll
            for (int i = 0; i < 16; ++i) oacc[i] *= sc;

            // ---- pack P to bf16 + half-swap into PV B-fragment layout ----
            // lane reg i holds k_local = (i&3) + 8*(i>>2) + 4*h32
            uint32_t a0 = pk2(p[0],  p[1]),  a1 = pk2(p[2],  p[3]);
            uint32_t b0 = pk2(p[4],  p[5]),  b1 = pk2(p[6],  p[7]);
            uint32_t c0 = pk2(p[8],  p[9]),  c1 = pk2(p[10], p[11]);
            uint32_t d0 = pk2(p[12], p[13]), d1 = pk2(p[14], p[15]);
            uint32_t sa0 = (uint32_t)__shfl_xor((int)a0, 32), sa1 = (uint32_t)__shfl_xor((int)a1, 32);
            uint32_t sb0 = (uint32_t)__shfl_xor((int)b0, 32), sb1 = (uint32_t)__shfl_xor((int)b1, 32);
            uint32_t sc0 = (uint32_t)__shfl_xor((int)c0, 32), sc1 = (uint32_t)__shfl_xor((int)c1, 32);
            uint32_t sd0 = (uint32_t)__shfl_xor((int)d0, 32), sd1 = (uint32_t)__shfl_xor((int)d1, 32);
            const bool hh = (h32 != 0);
            U4 p0, p1;
            p0.w[0] = hh ? sb0 : a0;  p0.w[1] = hh ? sb1 : a1;   // k 0..3 / 8..11
            p0.w[2] = hh ? b0  : sa0; p0.w[3] = hh ? b1  : sa1;  // k 4..7 / 12..15
            p1.w[0] = hh ? sd0 : c0;  p1.w[1] = hh ? sd1 : c1;   // k 16..19 / 24..27
            p1.w[2] = hh ? d0  : sc0; p1.w[3] = hh ? d1  : sc1;  // k 20..23 / 28..31

            // ---- PV: O^T[c][q] += V^T * P^T ----
            const char* vr = (const char*)lvt + l31 * 144 + ks * 64 + h32 * 16;
            bf16x8 v0 = __builtin_bit_cast(bf16x8, *(const U4*)vr);
            bf16x8 v1 = __builtin_bit_cast(bf16x8, *(const U4*)(vr + 32));
            oacc = MFMA32(v0, __builtin_bit_cast(bf16x8, p0), oacc);
            oacc = MFMA32(v1, __builtin_bit_cast(bf16x8, p1), oacc);
        }
        __syncthreads();
    }

    // ---- epilogue: normalize, write O^T -> out[b][c][n] ----
    const float inv = 1.f / l_run;
    float* ob = out + ((size_t)b * 32) * 4096 + qrow;
    #pragma unroll
    for (int i = 0; i < 16; ++i) {
        int c = (i & 3) + 8 * (i >> 2) + 4 * h32;
        ob[(size_t)c * 4096] = oacc[i] * inv;
    }
}

// ---------------------------------------------------------------------------
extern "C" void kernel_launch(void* const* d_in, const int* in_sizes, int n_in,
                              void* d_out, int out_size, void* d_ws, size_t ws_size,
                              hipStream_t stream)
{
    (void)in_sizes; (void)n_in; (void)out_size; (void)ws_size;
    const float* x  = (const float*)d_in[0];
    const float* Wk = (const float*)d_in[1];
    const float* bk = (const float*)d_in[2];
    const float* Wq = (const float*)d_in[3];
    const float* bq = (const float*)d_in[4];
    const float* Wv = (const float*)d_in[5];
    const float* bv = (const float*)d_in[6];
    float* out = (float*)d_out;

    char* ws = (char*)d_ws;
    const size_t SZ = (size_t)8 * 4096 * 32 * 2;   // 2 MB per buffer
    uint16_t* qhi = (uint16_t*)(ws);
    uint16_t* qlo = (uint16_t*)(ws + SZ);
    uint16_t* khi = (uint16_t*)(ws + 2 * SZ);
    uint16_t* klo = (uint16_t*)(ws + 3 * SZ);
    uint16_t* vt  = (uint16_t*)(ws + 4 * SZ);

    proj_kernel<<<128, 256, 0, stream>>>(x, Wk, bk, Wq, bq, Wv, bv,
                                         qhi, qlo, khi, klo, vt);
    attn_kernel<<<256, 256, 0, stream>>>(qhi, qlo, khi, klo, vt, out);
}

// Round 2
// 101.155 us; speedup vs baseline: 1.8002x; 1.8002x over previous
//
#include <hip/hip_runtime.h>
#include <hip/hip_bf16.h>
#include <cstdint>
#include <cstddef>

// ---------------------------------------------------------------------------
// KQV2DPixel: 1x1-conv projections + flash attention, B=8, Cin=64, Cm=32,
// N=4096. fp32 in/out. Split-bf16 QK^T (hi+lo), log2-domain online softmax,
// cvt_pk+permlane32_swap P-packing, K-split x ns with reduce kernel.
// ---------------------------------------------------------------------------

typedef __bf16 bf16x8 __attribute__((ext_vector_type(8)));
typedef float  f32x16 __attribute__((ext_vector_type(16)));
typedef float  f32x4  __attribute__((ext_vector_type(4)));

struct alignas(16) U4 { uint32_t w[4]; };

#define MFMA32(A, B, C) __builtin_amdgcn_mfma_f32_32x32x16_bf16((A), (B), (C), 0, 0, 0)

__device__ __forceinline__ uint16_t f2bf(float f) {
    uint32_t u = __builtin_bit_cast(uint32_t, f);
    u += 0x7fffu + ((u >> 16) & 1u);       // RNE
    return (uint16_t)(u >> 16);
}
__device__ __forceinline__ float bf2f(uint16_t h) {
    uint32_t u = ((uint32_t)h) << 16;
    return __builtin_bit_cast(float, u);
}
__device__ __forceinline__ uint32_t cvtpk(float lo, float hi) {
    uint32_t r;
    asm("v_cvt_pk_bf16_f32 %0, %1, %2" : "=v"(r) : "v"(lo), "v"(hi));
    return r;
}
__device__ __forceinline__ void swp(uint32_t& a, uint32_t& b) {
    // vdst[63:32] <-> vsrc[31:0]: a' = {a.lo, b.lo_old}, b' = {a.hi_old, b.hi}
    asm("v_permlane32_swap_b32 %0, %1" : "+v"(a), "+v"(b));
}
__device__ __forceinline__ float ex2(float x) {   // 2^x
    float r;
    asm("v_exp_f32 %0, %1" : "=v"(r) : "v"(x));
    return r;
}

// ---------------------------------------------------------------------------
// Kernel 1: projections. grid 256 x 256. 2 threads/pixel (wave-uniform output
// half -> W streamed through SGPRs via scalar loads; no LDS). x in registers.
//   k,q: hi+lo bf16, [B][N][32]; q pre-scaled by log2(e).  v: bf16 [B][32][N].
// ---------------------------------------------------------------------------
__global__ __launch_bounds__(256) void proj_kernel(
    const float* __restrict__ x,
    const float* __restrict__ Wk, const float* __restrict__ bk,
    const float* __restrict__ Wq, const float* __restrict__ bq,
    const float* __restrict__ Wv, const float* __restrict__ bv,
    uint16_t* __restrict__ qhi, uint16_t* __restrict__ qlo,
    uint16_t* __restrict__ khi, uint16_t* __restrict__ klo,
    uint16_t* __restrict__ vt)
{
    const int tid  = threadIdx.x;
    const int lane = tid & 63;
    const int half = __builtin_amdgcn_readfirstlane((tid >> 6) & 1);  // wave-uniform
    const int pxl  = ((tid >> 7) << 6) + lane;   // 0..127
    const int b     = blockIdx.x >> 5;
    const int nbase = (blockIdx.x & 31) << 7;
    const int n     = nbase + pxl;
    const int ob    = half << 4;                 // output half base

    const float* xb = x + (size_t)b * 64 * 4096 + n;
    float xv[64];
    #pragma unroll
    for (int ci = 0; ci < 64; ++ci) xv[ci] = xb[(size_t)ci * 4096];

    #pragma unroll
    for (int pass = 0; pass < 3; ++pass) {
        const float* W    = pass == 0 ? Wk : (pass == 1 ? Wq : Wv);
        const float* bias = pass == 0 ? bk : (pass == 1 ? bq : bv);
        float acc[16];
        #pragma unroll
        for (int o = 0; o < 16; ++o) acc[o] = bias[ob + o];
        #pragma unroll
        for (int o = 0; o < 16; ++o) {
            const float* wr = W + (size_t)(ob + o) * 64;   // uniform -> s_load
            #pragma unroll
            for (int ci = 0; ci < 64; ++ci)
                acc[o] = fmaf(wr[ci], xv[ci], acc[o]);
        }
        if (pass == 2) {
            #pragma unroll
            for (int o = 0; o < 16; ++o)
                vt[((size_t)(b * 32 + ob + o)) * 4096 + n] = f2bf(acc[o]);
        } else {
            if (pass == 1) {
                #pragma unroll
                for (int o = 0; o < 16; ++o) acc[o] *= 1.44269504f;   // log2(e)
            }
            uint32_t hp[8], lp[8];
            #pragma unroll
            for (int j = 0; j < 8; ++j) {
                float a0 = acc[2 * j], a1 = acc[2 * j + 1];
                uint16_t h0 = f2bf(a0), h1 = f2bf(a1);
                hp[j] = (uint32_t)h0 | ((uint32_t)h1 << 16);
                uint16_t l0 = f2bf(a0 - bf2f(h0)), l1 = f2bf(a1 - bf2f(h1));
                lp[j] = (uint32_t)l0 | ((uint32_t)l1 << 16);
            }
            uint16_t* hd = (pass ? qhi : khi) + ((size_t)(b * 4096 + n)) * 32 + ob;
            uint16_t* ld = (pass ? qlo : klo) + ((size_t)(b * 4096 + n)) * 32 + ob;
            *(U4*)hd       = *(U4*)&hp[0];
            *(U4*)(hd + 8) = *(U4*)&hp[4];
            *(U4*)ld       = *(U4*)&lp[0];
            *(U4*)(ld + 8) = *(U4*)&lp[4];
        }
    }
}

// ---------------------------------------------------------------------------
// Kernel 2: flash attention with K-split. grid ns*256, 256 thr = 4 waves.
// b = blockIdx&7 (XCD-aligned: batch b's K/V stays in XCD b's L2).
// Per block: 128 q rows x (64/ns) 64-key tiles. One softmax per 64 keys.
// ns==1 -> write normalized out; ns>1 -> unnormalized O + (m,l) partials.
// ---------------------------------------------------------------------------
__global__ __launch_bounds__(256, 4) void attn_kernel(
    const uint16_t* __restrict__ qhi, const uint16_t* __restrict__ qlo,
    const uint16_t* __restrict__ khi, const uint16_t* __restrict__ klo,
    const uint16_t* __restrict__ vt, float* __restrict__ out,
    float* __restrict__ opart, float* __restrict__ mpart,
    float* __restrict__ lpart, int ns)
{
    __shared__ __align__(16) uint16_t lkh[64 * 40];   // K hi tile, 80B rows
    __shared__ __align__(16) uint16_t lkl[64 * 40];   // K lo tile
    __shared__ __align__(16) uint16_t lvt[32 * 72];   // V^T tile, 144B rows

    const int blk    = blockIdx.x;
    const int b      = blk & 7;                 // XCD-aligned batch
    const int rest   = blk >> 3;
    const int qblk   = rest & 31;
    const int ksp    = rest >> 5;               // 0..ns-1
    const int ntiles = 64 / ns;
    const int kb0    = ksp * ntiles;

    const int tid  = threadIdx.x;
    const int wv   = tid >> 6;
    const int lane = tid & 63;
    const int l31  = lane & 31;
    const int h32  = lane >> 5;
    const int qrow = qblk * 128 + wv * 32 + l31;

    bf16x8 qh0, qh1, ql0, ql1;
    {
        const uint16_t* r = qhi + ((size_t)(b * 4096 + qrow)) * 32;
        qh0 = __builtin_bit_cast(bf16x8, *(const U4*)(r + h32 * 8));
        qh1 = __builtin_bit_cast(bf16x8, *(const U4*)(r + 16 + h32 * 8));
        const uint16_t* r2 = qlo + ((size_t)(b * 4096 + qrow)) * 32;
        ql0 = __builtin_bit_cast(bf16x8, *(const U4*)(r2 + h32 * 8));
        ql1 = __builtin_bit_cast(bf16x8, *(const U4*)(r2 + 16 + h32 * 8));
    }

    f32x16 oacc;
    #pragma unroll
    for (int i = 0; i < 16; ++i) oacc[i] = 0.f;
    float m_run = -3.0e38f, l_run = 0.f;

    const U4* gkh = (const U4*)(khi + ((size_t)b * 4096) * 32);
    const U4* gkl = (const U4*)(klo + ((size_t)b * 4096) * 32);
    const uint16_t* gv = vt + ((size_t)b * 32) * 4096;

    #pragma unroll 1
    for (int kb = kb0; kb < kb0 + ntiles; ++kb) {
        // ---- stage K hi/lo (64x32) and V^T (32x64) ----
        {
            U4 a = gkh[kb * 256 + tid];
            U4 c = gkl[kb * 256 + tid];
            U4 v = *(const U4*)(gv + ((size_t)(tid >> 3)) * 4096 + kb * 64 + (tid & 7) * 8);
            *(U4*)((char*)lkh + (tid >> 2) * 80 + (tid & 3) * 16) = a;
            *(U4*)((char*)lkl + (tid >> 2) * 80 + (tid & 3) * 16) = c;
            *(U4*)((char*)lvt + (tid >> 3) * 144 + (tid & 7) * 16) = v;
        }
        __syncthreads();

        // ---- QK^T, both 32-key halves (independent MFMA chains) ----
        f32x16 s0, s1;
        #pragma unroll
        for (int i = 0; i < 16; ++i) { s0[i] = 0.f; s1[i] = 0.f; }
        {
            const char* kr = (const char*)lkh + l31 * 80 + h32 * 16;
            const char* lr = (const char*)lkl + l31 * 80 + h32 * 16;
            bf16x8 a0 = __builtin_bit_cast(bf16x8, *(const U4*)kr);
            bf16x8 a1 = __builtin_bit_cast(bf16x8, *(const U4*)(kr + 32));
            bf16x8 b0 = __builtin_bit_cast(bf16x8, *(const U4*)lr);
            bf16x8 b1 = __builtin_bit_cast(bf16x8, *(const U4*)(lr + 32));
            s0 = MFMA32(a0, qh0, s0);
            s0 = MFMA32(a1, qh1, s0);
            s0 = MFMA32(b0, qh0, s0);
            s0 = MFMA32(b1, qh1, s0);
            s0 = MFMA32(a0, ql0, s0);
            s0 = MFMA32(a1, ql1, s0);
        }
        {
            const char* kr = (const char*)lkh + (32 + l31) * 80 + h32 * 16;
            const char* lr = (const char*)lkl + (32 + l31) * 80 + h32 * 16;
            bf16x8 a0 = __builtin_bit_cast(bf16x8, *(const U4*)kr);
            bf16x8 a1 = __builtin_bit_cast(bf16x8, *(const U4*)(kr + 32));
            bf16x8 b0 = __builtin_bit_cast(bf16x8, *(const U4*)lr);
            bf16x8 b1 = __builtin_bit_cast(bf16x8, *(const U4*)(lr + 32));
            s1 = MFMA32(a0, qh0, s1);
            s1 = MFMA32(a1, qh1, s1);
            s1 = MFMA32(b0, qh0, s1);
            s1 = MFMA32(b1, qh1, s1);
            s1 = MFMA32(a0, ql0, s1);
            s1 = MFMA32(a1, ql1, s1);
        }

        // ---- one online-softmax update per 64 keys (log2 domain) ----
        float mx[8];
        #pragma unroll
        for (int i = 0; i < 8; ++i)
            mx[i] = fmaxf(fmaxf(s0[i], s0[i + 8]), fmaxf(s1[i], s1[i + 8]));
        #pragma unroll
        for (int i = 0; i < 4; ++i) mx[i] = fmaxf(mx[i], mx[i + 4]);
        float pm = fmaxf(fmaxf(mx[0], mx[2]), fmaxf(mx[1], mx[3]));
        pm = fmaxf(pm, __shfl_xor(pm, 32));

        if (__any(pm > m_run)) {          // skip rescale when no row grew
            float mn  = fmaxf(m_run, pm);
            float scl = ex2(m_run - mn);
            l_run *= scl;
            #pragma unroll
            for (int i = 0; i < 16; ++i) oacc[i] *= scl;
            m_run = mn;
        }

        #pragma unroll
        for (int i = 0; i < 16; ++i) {
            s0[i] = ex2(s0[i] - m_run);
            s1[i] = ex2(s1[i] - m_run);
        }
        float sm[8];
        #pragma unroll
        for (int i = 0; i < 8; ++i)
            sm[i] = (s0[i] + s0[i + 8]) + (s1[i] + s1[i + 8]);
        #pragma unroll
        for (int i = 0; i < 4; ++i) sm[i] += sm[i + 4];
        float rs = (sm[0] + sm[2]) + (sm[1] + sm[3]);
        rs += __shfl_xor(rs, 32);
        l_run += rs;

        // ---- pack P -> 4 bf16x8 B-fragments (cvt_pk + permlane32_swap) ----
        U4 f1, f2, f3, f4;
        {
            uint32_t A = cvtpk(s0[0], s0[1]),  B = cvtpk(s0[4], s0[5]);   swp(A, B);
            uint32_t C = cvtpk(s0[2], s0[3]),  D = cvtpk(s0[6], s0[7]);   swp(C, D);
            f1.w[0] = A; f1.w[1] = C; f1.w[2] = B; f1.w[3] = D;
            A = cvtpk(s0[8], s0[9]);   B = cvtpk(s0[12], s0[13]);  swp(A, B);
            C = cvtpk(s0[10], s0[11]); D = cvtpk(s0[14], s0[15]);  swp(C, D);
            f2.w[0] = A; f2.w[1] = C; f2.w[2] = B; f2.w[3] = D;
            A = cvtpk(s1[0], s1[1]);   B = cvtpk(s1[4], s1[5]);    swp(A, B);
            C = cvtpk(s1[2], s1[3]);   D = cvtpk(s1[6], s1[7]);    swp(C, D);
            f3.w[0] = A; f3.w[1] = C; f3.w[2] = B; f3.w[3] = D;
            A = cvtpk(s1[8], s1[9]);   B = cvtpk(s1[12], s1[13]);  swp(A, B);
            C = cvtpk(s1[10], s1[11]); D = cvtpk(s1[14], s1[15]);  swp(C, D);
            f4.w[0] = A; f4.w[1] = C; f4.w[2] = B; f4.w[3] = D;
        }

        // ---- PV: O^T[c][q] += V^T * P^T  (4 MFMAs over 64 keys) ----
        {
            const char* vr = (const char*)lvt + l31 * 144 + h32 * 16;
            bf16x8 v0 = __builtin_bit_cast(bf16x8, *(const U4*)vr);
            bf16x8 v1 = __builtin_bit_cast(bf16x8, *(const U4*)(vr + 32));
            bf16x8 v2 = __builtin_bit_cast(bf16x8, *(const U4*)(vr + 64));
            bf16x8 v3 = __builtin_bit_cast(bf16x8, *(const U4*)(vr + 96));
            oacc = MFMA32(v0, __builtin_bit_cast(bf16x8, f1), oacc);
            oacc = MFMA32(v1, __builtin_bit_cast(bf16x8, f2), oacc);
            oacc = MFMA32(v2, __builtin_bit_cast(bf16x8, f3), oacc);
            oacc = MFMA32(v3, __builtin_bit_cast(bf16x8, f4), oacc);
        }
        __syncthreads();
    }

    // ---- epilogue ----
    if (ns == 1) {
        const float inv = 1.f / l_run;
        float* ob = out + ((size_t)b * 32) * 4096 + qrow;
        #pragma unroll
        for (int i = 0; i < 16; ++i) {
            int c = (i & 3) + 8 * (i >> 2) + 4 * h32;
            ob[(size_t)c * 4096] = oacc[i] * inv;
        }
    } else {
        float* op = opart + ((size_t)((ksp * 8 + b) * 32)) * 4096 + qrow;
        #pragma unroll
        for (int i = 0; i < 16; ++i) {
            int c = (i & 3) + 8 * (i >> 2) + 4 * h32;
            op[(size_t)c * 4096] = oacc[i];
        }
        if (h32 == 0) {
            mpart[((size_t)(ksp * 8 + b)) * 4096 + qrow] = m_run;
            lpart[((size_t)(ksp * 8 + b)) * 4096 + qrow] = l_run;
        }
    }
}

// ---------------------------------------------------------------------------
// Kernel 3: combine K-split partials. thread = (b, c, 4 pixels).
// ---------------------------------------------------------------------------
__global__ __launch_bounds__(256) void reduce_kernel(
    const float* __restrict__ opart, const float* __restrict__ mpart,
    const float* __restrict__ lpart, float* __restrict__ out, int ns)
{
    const int idx = blockIdx.x * 256 + threadIdx.x;   // 262144 quads
    const int nq  = idx & 1023;
    const int c   = (idx >> 10) & 31;
    const int b   = idx >> 15;
    const size_t noff = (size_t)nq * 4;

    f32x4 M;
    #pragma unroll
    for (int e = 0; e < 4; ++e) M[e] = -3.0e38f;
    for (int s = 0; s < ns; ++s) {
        f32x4 mm = *(const f32x4*)(mpart + ((size_t)(s * 8 + b)) * 4096 + noff);
        #pragma unroll
        for (int e = 0; e < 4; ++e) M[e] = fmaxf(M[e], mm[e]);
    }
    f32x4 L, O;
    #pragma unroll
    for (int e = 0; e < 4; ++e) { L[e] = 0.f; O[e] = 0.f; }
    for (int s = 0; s < ns; ++s) {
        f32x4 mm = *(const f32x4*)(mpart + ((size_t)(s * 8 + b)) * 4096 + noff);
        f32x4 ll = *(const f32x4*)(lpart + ((size_t)(s * 8 + b)) * 4096 + noff);
        f32x4 oo = *(const f32x4*)(opart + ((size_t)((s * 8 + b) * 32 + c)) * 4096 + noff);
        #pragma unroll
        for (int e = 0; e < 4; ++e) {
            float w = ex2(mm[e] - M[e]);
            L[e] += ll[e] * w;
            O[e] += oo[e] * w;
        }
    }
    f32x4 r;
    #pragma unroll
    for (int e = 0; e < 4; ++e) r[e] = O[e] / L[e];
    *(f32x4*)(out + ((size_t)(b * 32 + c)) * 4096 + noff) = r;
}

// ---------------------------------------------------------------------------
extern "C" void kernel_launch(void* const* d_in, const int* in_sizes, int n_in,
                              void* d_out, int out_size, void* d_ws, size_t ws_size,
                              hipStream_t stream)
{
    (void)in_sizes; (void)n_in; (void)out_size;
    const float* x  = (const float*)d_in[0];
    const float* Wk = (const float*)d_in[1];
    const float* bk = (const float*)d_in[2];
    const float* Wq = (const float*)d_in[3];
    const float* bq = (const float*)d_in[4];
    const float* Wv = (const float*)d_in[5];
    const float* bv = (const float*)d_in[6];
    float* out = (float*)d_out;

    char* ws = (char*)d_ws;
    const size_t SZ = (size_t)8 * 4096 * 32 * 2;   // 2 MB per bf16 buffer
    uint16_t* qhi = (uint16_t*)(ws);
    uint16_t* qlo = (uint16_t*)(ws + SZ);
    uint16_t* khi = (uint16_t*)(ws + 2 * SZ);
    uint16_t* klo = (uint16_t*)(ws + 3 * SZ);
    uint16_t* vt  = (uint16_t*)(ws + 4 * SZ);
    const size_t base = 5 * SZ;                    // 10 MB

    const size_t OB  = (size_t)8 * 32 * 4096 * 4;  // 4 MB per split (O^T)
    const size_t MB_ = (size_t)8 * 4096 * 4;       // 128 KB per split (m or l)
    int ns = 1;
    if      (ws_size >= base + 4 * (OB + 2 * MB_)) ns = 4;
    else if (ws_size >= base + 2 * (OB + 2 * MB_)) ns = 2;

    float* opart = (float*)(ws + base);
    float* mpart = (float*)(ws + base + (size_t)ns * OB);
    float* lpart = (float*)(ws + base + (size_t)ns * OB + (size_t)ns * MB_);

    proj_kernel<<<256, 256, 0, stream>>>(x, Wk, bk, Wq, bq, Wv, bv,
                                         qhi, qlo, khi, klo, vt);
    attn_kernel<<<ns * 256, 256, 0, stream>>>(qhi, qlo, khi, klo, vt, out,
                                              opart, mpart, lpart, ns);
    if (ns > 1)
        reduce_kernel<<<1024, 256, 0, stream>>>(opart, mpart, lpart, out, ns);
}